// Round 4
// baseline (371.671 us; speedup 1.0000x reference)
//
#include <hip/hip_runtime.h>
#include <math.h>

#define GRIDN   1024
#define NELEM   262144            // 4*64*32*32
#define NPAIRW  18432             // 64 o * 32 pairs * 9
#define PIMG    1296              // 36*36 padded image stride per (b,pair)
#define PPADN   165888            // 4*32*36*36 words
#define NPAIR   147968            // 4*32*34*34
#define EPS_BN  1e-5f
#define QSC     128.0f
#define QBIAS_F 16384.5f          // bias 16384 + 0.5 rounding
#define QZ_W    0x40004000u       // packed quantized zero
#define QINV    (1.0f / 128.0f)

// v_sad_u16: acc += |a.lo-b.lo| + |a.hi-b.hi|  (two terms per instruction)
__device__ __forceinline__ unsigned sad16(unsigned a, unsigned b, unsigned acc) {
    asm("v_sad_u16 %0, %1, %2, %0" : "+v"(acc) : "v"(a), "v"(b));
    return acc;
}
__device__ __forceinline__ unsigned qu(float v) {
    return (unsigned)(int)fmaf(v, QSC, QBIAS_F);
}

// ---------------------------------------------------------------------------
// Software grid barrier (grid exactly GRIDN blocks, all co-resident by
// occupancy arithmetic: 4 blocks/CU x 256 CU). __threadfence() is an
// agent-scope fence (L2 writeback/invalidate across XCDs) — same primitive
// cg::grid.sync() uses; only the cooperative *launch API* fails in capture.
// ---------------------------------------------------------------------------
__device__ __forceinline__ void gridbar(unsigned* cnt, int t) {
    __syncthreads();                       // all block stores issued+complete
    if (t == 0) {
        __threadfence();                   // release: publish to LLC
        __hip_atomic_fetch_add(cnt, 1u, __ATOMIC_ACQ_REL, __HIP_MEMORY_SCOPE_AGENT);
        while (__hip_atomic_load(cnt, __ATOMIC_RELAXED, __HIP_MEMORY_SCOPE_AGENT) < GRIDN)
            __builtin_amdgcn_s_sleep(2);
        __threadfence();                   // acquire: invalidate stale caches
    }
    __syncthreads();
}

// ---------------------------------------------------------------------------
// Adder2d phase on pair-packed u16 data (R1-verified body, bn2 inlined).
// blk: b(4) x og(32: 2 outs) x sp(8: 4-row strips); 256 threads.
// MODE 0: writes quant(relu(bn2(-acc))) u16 half into packed qout.
// MODE 1: writes float out2 + SE spatial-sum atomics into sbuf.
// ---------------------------------------------------------------------------
template<int MODE>
__device__ __forceinline__ void adder_phase(
    unsigned (*wlds)[32][12], unsigned (*red)[32][9],
    const unsigned* __restrict__ qsrc, const unsigned* __restrict__ qwp,
    const float* __restrict__ g2, const float* __restrict__ b2,
    const float* __restrict__ m2, const float* __restrict__ v2,
    unsigned* __restrict__ qout, float* __restrict__ fout,
    float* __restrict__ sbuf, int blk, int t)
{
    const int sp  = blk & 7;                 // rows [sp*4, sp*4+4)
    const int og  = (blk >> 3) & 31;
    const int b   = blk >> 8;
    const int pos = t & 31;
    const int cq  = t >> 5;                  // 0..7, 4 pairs each
    const int y_i = pos >> 3;                // 0..3
    const int x0  = (pos & 7) * 4;           // 0..28

    // weight staging: 2 o x 32 pairs x 9 words (~2.25 words/thread)
    for (int i = t; i < 576; i += 256) {
        int o_i = i / 288;
        int rem = i - o_i * 288;
        int pr  = rem / 9;
        int kk  = rem - pr * 9;
        wlds[o_i][pr][kk] = qwp[((og * 2 + o_i) * 32 + pr) * 9 + kk];
    }
    __syncthreads();

    unsigned acc[2][4];
#pragma unroll
    for (int oo = 0; oo < 2; ++oo)
#pragma unroll
        for (int xi = 0; xi < 4; ++xi) acc[oo][xi] = 0u;

#pragma unroll
    for (int j = 0; j < 4; ++j) {
        const int pr = cq * 4 + j;
        const unsigned* pc = qsrc + (size_t)(b * 32 + pr) * PIMG
                                  + (sp * 4 + y_i) * 36 + x0;
        unsigned p[3][6];                    // 6 words/row: x4 + x2 loads
#pragma unroll
        for (int r = 0; r < 3; ++r) {
            uint4 a0 = *reinterpret_cast<const uint4*>(pc + r * 36);
            uint2 a1 = *reinterpret_cast<const uint2*>(pc + r * 36 + 4);
            p[r][0] = a0.x; p[r][1] = a0.y; p[r][2] = a0.z; p[r][3] = a0.w;
            p[r][4] = a1.x; p[r][5] = a1.y;
        }
#pragma unroll
        for (int oo = 0; oo < 2; ++oo) {
            uint4 wa = *reinterpret_cast<const uint4*>(&wlds[oo][pr][0]);
            uint4 wb = *reinterpret_cast<const uint4*>(&wlds[oo][pr][4]);
            unsigned w8 = wlds[oo][pr][8];
            unsigned wv[9] = {wa.x, wa.y, wa.z, wa.w,
                              wb.x, wb.y, wb.z, wb.w, w8};
#pragma unroll
            for (int kh = 0; kh < 3; ++kh)
#pragma unroll
                for (int kw = 0; kw < 3; ++kw) {
                    unsigned ww = wv[kh * 3 + kw];
#pragma unroll
                    for (int xi = 0; xi < 4; ++xi)
                        acc[oo][xi] = sad16(p[kh][xi + kw], ww, acc[oo][xi]);
                }
        }
    }

    // ---- cq reduction via LDS (stride-9 padded: conflict-free writes) ----
    {
        unsigned* dst = &red[cq][pos][0];
#pragma unroll
        for (int z = 0; z < 8; ++z) dst[z] = acc[z >> 2][z & 3];
    }
    __syncthreads();

    // 256 outputs: 2 o x 4 rows x 32 cols — every thread produces one
    const int oo2 = t >> 7;                  // wave-pair uniform
    const int yy2 = (t >> 5) & 3;
    const int xx2 = t & 31;
    const int pp  = yy2 * 8 + (xx2 >> 2);
    const int z   = oo2 * 4 + (xx2 & 3);
    unsigned total = 0;
#pragma unroll
    for (int q = 0; q < 8; ++q) total += red[q][pp][z];

    const int o  = og * 2 + oo2;             // wave-uniform
    const int gy = sp * 4 + yy2;

    if (MODE == 0) {
        // bn2 consts inline (wave-uniform o -> broadcast loads; R3-verified)
        float inv = g2[o] * rsqrtf(v2[o] + EPS_BN);
        float cc0 = -inv * QINV;
        float cc1 = b2[o] - m2[o] * inv;
        float a2  = fmaxf(fmaf((float)total, cc0, cc1), 0.f);
        unsigned short qv = (unsigned short)(int)fmaf(a2, QSC, QBIAS_F);
        size_t widx = (size_t)(b * 32 + (o >> 1)) * PIMG + (gy + 1) * 36 + (xx2 + 1);
        reinterpret_cast<unsigned short*>(qout)[widx * 2 + (o & 1)] = qv;
    } else {
        float v = -(float)total * QINV;
        fout[((b * 64 + o) * 32 + gy) * 32 + xx2] = v;
        float sum = v;                        // wave covers 2 rows of same o
#pragma unroll
        for (int off = 32; off > 0; off >>= 1)
            sum += __shfl_down(sum, off, 64);
        if ((t & 63) == 0) atomicAdd(&sbuf[b * 64 + o], sum);
    }
}

// ---------------------------------------------------------------------------
// One fused kernel (NORMAL launch), 4 phases with software grid barriers:
//   A) prep (coalesced quantize/pack of x and w1/w2, qout1p halo)
//   B) adder layer 1 (MODE 0)    C) adder layer 2 (MODE 1)
//   D) SE gate + apply + shortcut (blocks 0..255)
// Grid 1024 x 256, __launch_bounds__(256,4), 12.3 KB LDS -> exactly 4
// blocks/CU x 256 CU = 1024 co-resident.
// ---------------------------------------------------------------------------
__global__ __launch_bounds__(256, 4) void fused_kernel(
    const float* __restrict__ x,
    const float* __restrict__ g1, const float* __restrict__ b1,
    const float* __restrict__ m1, const float* __restrict__ v1,
    const float* __restrict__ w1,
    const float* __restrict__ g2, const float* __restrict__ b2,
    const float* __restrict__ m2, const float* __restrict__ v2,
    const float* __restrict__ w2,
    const float* __restrict__ fc1w, const float* __restrict__ fc1b,
    const float* __restrict__ fc2w, const float* __restrict__ fc2b,
    float* __restrict__ sbuf, unsigned* __restrict__ cnt,
    unsigned* __restrict__ qxp, unsigned* __restrict__ qout1p,
    unsigned* __restrict__ qw1p, unsigned* __restrict__ qw2p,
    float* __restrict__ out2, float* __restrict__ out)
{
    __shared__ unsigned smem[3072];          // 12288 B
    unsigned (*wlds)[32][12] = reinterpret_cast<unsigned(*)[32][12]>(smem);        // 768 w
    unsigned (*red)[32][9]   = reinterpret_cast<unsigned(*)[32][9]>(smem + 768);   // 2304 w

    const int blk = blockIdx.x;
    const int t   = threadIdx.x;

    // ---------------- phase A: prep (R1-verified, coalesced) ----------------
    {
        int i = blk * 256 + t;
        if (i < NPAIR) {
            int bp  = i / 1156;                       // b*32 + pair
            int rc  = i - bp * 1156;
            int r   = rc / 34;
            int col = rc - r * 34;
            bool interior = (r > 0 && r < 33 && col > 0 && col < 33);
            unsigned q = QZ_W;
            if (interior) {
                int b  = bp >> 5;
                int c0 = (bp & 31) * 2;
                float inv0 = g1[c0] * rsqrtf(v1[c0] + EPS_BN);
                float bet0 = b1[c0] - m1[c0] * inv0;
                float inv1 = g1[c0 + 1] * rsqrtf(v1[c0 + 1] + EPS_BN);
                float bet1 = b1[c0 + 1] - m1[c0 + 1] * inv1;
                int off = (b * 64 + c0) * 1024 + (r - 1) * 32 + (col - 1);
                float a0 = fmaxf(fmaf(x[off],        inv0, bet0), 0.f);
                float a1 = fmaxf(fmaf(x[off + 1024], inv1, bet1), 0.f);
                q = qu(a0) | (qu(a1) << 16);
            }
            int pidx = bp * PIMG + r * 36 + col;
            qxp[pidx] = q;
            if (!interior) qout1p[pidx] = QZ_W;
        } else {
            int k = i - NPAIR;
            if (k < NPAIRW) {
                int o   = k / 288;
                int rem = k - o * 288;
                int pr  = rem / 9;
                int kk  = rem - pr * 9;
                int woff = (o * 64 + pr * 2) * 9 + kk;
                qw1p[k] = qu(w1[woff]) | (qu(w1[woff + 9]) << 16);
            } else {
                int l = k - NPAIRW;
                if (l < NPAIRW) {
                    int o   = l / 288;
                    int rem = l - o * 288;
                    int pr  = rem / 9;
                    int kk  = rem - pr * 9;
                    int woff = (o * 64 + pr * 2) * 9 + kk;
                    qw2p[l] = qu(w2[woff]) | (qu(w2[woff + 9]) << 16);
                }
            }
        }
    }
    gridbar(cnt + 0, t);

    // ---------------- phase B: adder layer 1 ----------------
    adder_phase<0>(wlds, red, qxp, qw1p, g2, b2, m2, v2,
                   qout1p, nullptr, nullptr, blk, t);
    gridbar(cnt + 16, t);

    // ---------------- phase C: adder layer 2 ----------------
    adder_phase<1>(wlds, red, qout1p, qw2p, nullptr, nullptr, nullptr, nullptr,
                   nullptr, out2, sbuf, blk, t);
    gridbar(cnt + 32, t);

    // ---------------- phase D: SE gate + apply + shortcut ----------------
    if (blk < 256) {
        const int bo = blk;
        const int b  = bo >> 6;
        const int o  = bo & 63;

        float* ss = reinterpret_cast<float*>(smem);
        if (t < 64) ss[t] = sbuf[b * 64 + t] * (1.f / 1024.f);
        __syncthreads();

        float h[4];
#pragma unroll
        for (int j = 0; j < 4; ++j) {
            float a = fc1b[j];
#pragma unroll
            for (int c = 0; c < 64; ++c) a += ss[c] * fc1w[j * 64 + c];
            h[j] = fmaxf(a, 0.f);
        }
        float zz = fc2b[o];
#pragma unroll
        for (int j = 0; j < 4; ++j) zz += h[j] * fc2w[o * 4 + j];
        float g = 1.f / (1.f + __expf(-zz));

        const int base = bo * 1024 + t * 4;
        float4 v  = *reinterpret_cast<const float4*>(out2 + base);
        float4 xv = *reinterpret_cast<const float4*>(x + base);
        float4 r;
        r.x = v.x * g + xv.x;
        r.y = v.y * g + xv.y;
        r.z = v.z * g + xv.z;
        r.w = v.w * g + xv.w;
        *reinterpret_cast<float4*>(out + base) = r;
    }
}

// ---------------------------------------------------------------------------
extern "C" void kernel_launch(void* const* d_in, const int* in_sizes, int n_in,
                              void* d_out, int out_size, void* d_ws, size_t ws_size,
                              hipStream_t stream)
{
    const float* x    = (const float*)d_in[0];
    const float* bn1g = (const float*)d_in[1];
    const float* bn1b = (const float*)d_in[2];
    const float* bn1m = (const float*)d_in[3];
    const float* bn1v = (const float*)d_in[4];
    const float* w1   = (const float*)d_in[5];
    const float* bn2g = (const float*)d_in[6];
    const float* bn2b = (const float*)d_in[7];
    const float* bn2m = (const float*)d_in[8];
    const float* bn2v = (const float*)d_in[9];
    const float* w2   = (const float*)d_in[10];
    const float* fc1w = (const float*)d_in[11];
    const float* fc1b = (const float*)d_in[12];
    const float* fc2w = (const float*)d_in[13];
    const float* fc2b = (const float*)d_in[14];

    unsigned* ws     = (unsigned*)d_ws;
    float*    sbuf   = (float*)ws;                      // 256 floats
    unsigned* cnt    = ws + 256;                        // 3 counters (16w apart)
    unsigned* qxp    = ws + 512;                        // PPADN
    unsigned* qout1p = ws + 512 + PPADN;                // PPADN
    unsigned* qw1p   = ws + 512 + 2 * PPADN;            // NPAIRW
    unsigned* qw2p   = ws + 512 + 2 * PPADN + NPAIRW;   // NPAIRW
    float*    out2   = (float*)(ws + 512 + 2 * PPADN + 2 * NPAIRW); // NELEM

    // zero sbuf + barrier counters (memset nodes ARE graph-capturable)
    hipMemsetAsync(d_ws, 0, 512 * sizeof(unsigned), stream);

    fused_kernel<<<GRIDN, 256, 0, stream>>>(
        x, bn1g, bn1b, bn1m, bn1v, w1,
        bn2g, bn2b, bn2m, bn2v, w2,
        fc1w, fc1b, fc2w, fc2b,
        sbuf, cnt, qxp, qout1p, qw1p, qw2p, out2, (float*)d_out);
}

// Round 5
// 198.467 us; speedup vs baseline: 1.8727x; 1.8727x over previous
//
#include <hip/hip_runtime.h>
#include <math.h>

#define NELEM   262144            // 4*64*32*32
#define PIMG    1296              // 36*36 padded image stride per (b,pair)
#define PPADN   165888            // 4*32*36*36 words
#define NHALO   16896             // 128 images * 132 halo words
#define EPS_BN  1e-5f
#define QSC     128.0f
#define QBIAS_F 16384.5f          // bias 16384 + 0.5 rounding
#define QZ_W    0x40004000u       // packed quantized zero
#define QINV    (1.0f / 128.0f)

// v_sad_u16: acc += |a.lo-b.lo| + |a.hi-b.hi|  (two terms per instruction)
__device__ __forceinline__ unsigned sad16(unsigned a, unsigned b, unsigned acc) {
    asm("v_sad_u16 %0, %1, %2, %0" : "+v"(acc) : "v"(a), "v"(b));
    return acc;
}
__device__ __forceinline__ unsigned qu(float v) {
    return (unsigned)(int)fmaf(v, QSC, QBIAS_F);
}

// ---------------------------------------------------------------------------
// adder1: prep fused with COALESCED staging (fixes R3's uncoalesced version).
// Grid 1024 = b(4) x og(32: 2 outs) x sp(8: 4-row strips); 256 threads,
// __launch_bounds__(256,4) -> 4 blocks/CU.
// Phases: QZ-fill xs + bn1 consts + w1-quant staging | barrier |
//         coalesced x load -> bn1+relu+quant -> u16 LDS half-writes | barrier |
//         SAD | barrier | cq-reduce (red aliases xs) | bn2-quant -> qout1p.
// Side duties: qout1p halo ring, sbuf zero, cnt zero.
// LDS: xs 27648B + wlds 3072B + bn consts 512B = 31232B -> 4 blocks/CU.
// ---------------------------------------------------------------------------
__global__ __launch_bounds__(256, 4) void adder1_kernel(
    const float* __restrict__ x,
    const float* __restrict__ g1, const float* __restrict__ b1,
    const float* __restrict__ m1, const float* __restrict__ v1,
    const float* __restrict__ w1,
    const float* __restrict__ g2, const float* __restrict__ b2,
    const float* __restrict__ m2, const float* __restrict__ v2,
    unsigned* __restrict__ qout, float* __restrict__ sbuf,
    unsigned* __restrict__ cnt)
{
    __shared__ unsigned smem[7808];                   // 31232 B
    unsigned (*xs)[6][36]    = reinterpret_cast<unsigned(*)[6][36]>(smem);         // 6912 w
    unsigned (*red)[32][9]   = reinterpret_cast<unsigned(*)[32][9]>(smem);         // aliases xs
    unsigned (*wlds)[32][12] = reinterpret_cast<unsigned(*)[32][12]>(smem + 6912); // 768 w
    float* binv = reinterpret_cast<float*>(smem + 7680);                           // 64 f
    float* bbet = binv + 64;                                                       // 64 f

    const int blk = blockIdx.x;
    const int sp  = blk & 7;                 // rows [sp*4, sp*4+4)
    const int og  = (blk >> 3) & 31;
    const int b   = blk >> 8;
    const int t   = threadIdx.x;

    // ---- side duties: sbuf zero (block 0), cnt zero (block 1), halo ring ----
    const int gid = blk * 256 + t;
    if (gid < 256) sbuf[gid] = 0.f;
    else if (gid < 272) cnt[gid - 256] = 0u;
    if (gid < NHALO) {
        int img = gid / 132;
        int j   = gid - img * 132;
        int r, c;
        if (j < 34)       { r = 0;           c = j;       }
        else if (j < 68)  { r = 33;          c = j - 34;  }
        else if (j < 100) { r = j - 68 + 1;  c = 0;       }
        else              { r = j - 100 + 1; c = 33;      }
        qout[img * PIMG + r * 36 + c] = QZ_W;
    }

    // ---- bn1 consts ----
    if (t < 64) {
        float iv = g1[t] * rsqrtf(v1[t] + EPS_BN);
        binv[t] = iv;
        bbet[t] = b1[t] - m1[t] * iv;
    }

    // ---- QZ fill of xs (padding cols 0,33..35 + out-of-range rows) ----
    for (int u = t; u < 1728; u += 256)      // 6912 words / 4
        reinterpret_cast<uint4*>(smem)[u] = make_uint4(QZ_W, QZ_W, QZ_W, QZ_W);

    // ---- w1 quant staging: contiguous slice og*1152 .. +1152, coalesced ----
    {
        unsigned short* wh = reinterpret_cast<unsigned short*>(wlds);
        const float* wbase = w1 + og * 1152;
        for (int u = t; u < 1152; u += 256) {
            int o_i = u / 576;
            int rem = u - o_i * 576;
            int c   = rem / 9;
            int kk  = rem - c * 9;
            wh[((o_i * 32 + (c >> 1)) * 12 + kk) * 2 + (c & 1)] =
                (unsigned short)qu(wbase[u]);
        }
    }
    __syncthreads();

    // ---- coalesced x staging: 6 rows x 64 ch x 32 cols, u16 half-writes ----
    {
        unsigned short* xh = reinterpret_cast<unsigned short*>(smem);
        for (int u = t; u < 12288; u += 256) {
            int lr  = u >> 11;               // 0..5
            int c   = (u >> 5) & 63;
            int col = u & 31;
            int xrow = sp * 4 + lr - 1;      // -1..34
            if ((unsigned)xrow < 32u) {
                float xv = x[(b * 64 + c) * 1024 + xrow * 32 + col];
                unsigned q = qu(fmaxf(fmaf(xv, binv[c], bbet[c]), 0.f));
                xh[((c >> 1) * 216 + lr * 36 + col + 1) * 2 + (c & 1)] =
                    (unsigned short)q;
            }
        }
    }
    __syncthreads();

    // ---- SAD compute (R3-verified body) ----
    const int pos = t & 31;
    const int cq  = t >> 5;                  // 0..7, 4 pairs each
    const int y_i = pos >> 3;                // 0..3
    const int x0  = (pos & 7) * 4;           // 0..28

    unsigned acc[2][4];
#pragma unroll
    for (int oo = 0; oo < 2; ++oo)
#pragma unroll
        for (int xi = 0; xi < 4; ++xi) acc[oo][xi] = 0u;

#pragma unroll
    for (int j = 0; j < 4; ++j) {
        const int pr = cq * 4 + j;
        unsigned p[3][6];
#pragma unroll
        for (int r = 0; r < 3; ++r) {
            const unsigned* src = &xs[pr][y_i + r][x0];
            uint4 a0 = *reinterpret_cast<const uint4*>(src);
            uint2 a1 = *reinterpret_cast<const uint2*>(src + 4);
            p[r][0] = a0.x; p[r][1] = a0.y; p[r][2] = a0.z; p[r][3] = a0.w;
            p[r][4] = a1.x; p[r][5] = a1.y;
        }
#pragma unroll
        for (int oo = 0; oo < 2; ++oo) {
            uint4 wa = *reinterpret_cast<const uint4*>(&wlds[oo][pr][0]);
            uint4 wb = *reinterpret_cast<const uint4*>(&wlds[oo][pr][4]);
            unsigned w8 = wlds[oo][pr][8];
            unsigned wv[9] = {wa.x, wa.y, wa.z, wa.w,
                              wb.x, wb.y, wb.z, wb.w, w8};
#pragma unroll
            for (int kh = 0; kh < 3; ++kh)
#pragma unroll
                for (int kw = 0; kw < 3; ++kw) {
                    unsigned ww = wv[kh * 3 + kw];
#pragma unroll
                    for (int xi = 0; xi < 4; ++xi)
                        acc[oo][xi] = sad16(p[kh][xi + kw], ww, acc[oo][xi]);
                }
        }
    }
    __syncthreads();                          // xs reads done before red aliases

    {
        unsigned* dst = &red[cq][pos][0];
#pragma unroll
        for (int z = 0; z < 8; ++z) dst[z] = acc[z >> 2][z & 3];
    }
    __syncthreads();

    const int oo2 = t >> 7;
    const int yy2 = (t >> 5) & 3;
    const int xx2 = t & 31;
    const int pp  = yy2 * 8 + (xx2 >> 2);
    const int z   = oo2 * 4 + (xx2 & 3);
    unsigned total = 0;
#pragma unroll
    for (int q = 0; q < 8; ++q) total += red[q][pp][z];

    const int o  = og * 2 + oo2;             // wave-uniform
    const int gy = sp * 4 + yy2;

    // bn2 consts inline (wave-uniform o -> broadcast loads; R3-verified)
    float inv = g2[o] * rsqrtf(v2[o] + EPS_BN);
    float cc0 = -inv * QINV;
    float cc1 = b2[o] - m2[o] * inv;
    float a2  = fmaxf(fmaf((float)total, cc0, cc1), 0.f);
    unsigned short qv = (unsigned short)(int)fmaf(a2, QSC, QBIAS_F);
    size_t widx = (size_t)(b * 32 + (o >> 1)) * PIMG + (gy + 1) * 36 + (xx2 + 1);
    reinterpret_cast<unsigned short*>(qout)[widx * 2 + (o & 1)] = qv;
}

// ---------------------------------------------------------------------------
// adder2: R1-verified layer-2 body + last-block-per-batch SE gate tail.
// Each block: one acq-rel ticket RMW on cnt[b] (no spin, no readers -> no
// R4 line-ping-pong pathology). Ticket==255 block (all of batch b done)
// computes SE MLP + applies gate for the whole batch (64 x 1024 float4s,
// independent iterations -> deep vmem pipelining on 4 waves).
// ---------------------------------------------------------------------------
__global__ __launch_bounds__(256, 4) void adder2_kernel(
    const unsigned* __restrict__ qsrc, const float* __restrict__ w2,
    const float* __restrict__ x,
    const float* __restrict__ fc1w, const float* __restrict__ fc1b,
    const float* __restrict__ fc2w, const float* __restrict__ fc2b,
    float* __restrict__ fout, float* __restrict__ sbuf,
    unsigned* __restrict__ cnt, float* __restrict__ out)
{
    __shared__ unsigned wlds[2][32][12];     // 3072 B
    __shared__ unsigned red[8][32][9];       // 9216 B
    __shared__ float gg[64];
    __shared__ float hh[4];
    __shared__ int lastflag;

    const int blk = blockIdx.x;
    const int sp  = blk & 7;
    const int og  = (blk >> 3) & 31;
    const int b   = blk >> 8;
    const int t   = threadIdx.x;
    const int pos = t & 31;
    const int cq  = t >> 5;
    const int y_i = pos >> 3;
    const int x0  = (pos & 7) * 4;

    // w2 quant staging (R3-verified)
    for (int i = t; i < 576; i += 256) {
        int o_i = i / 288;
        int rem = i - o_i * 288;
        int pr  = rem / 9;
        int kk  = rem - pr * 9;
        int woff = ((og * 2 + o_i) * 64 + pr * 2) * 9 + kk;
        wlds[o_i][pr][kk] = qu(w2[woff]) | (qu(w2[woff + 9]) << 16);
    }
    __syncthreads();

    unsigned acc[2][4];
#pragma unroll
    for (int oo = 0; oo < 2; ++oo)
#pragma unroll
        for (int xi = 0; xi < 4; ++xi) acc[oo][xi] = 0u;

#pragma unroll
    for (int j = 0; j < 4; ++j) {
        const int pr = cq * 4 + j;
        const unsigned* pc = qsrc + (size_t)(b * 32 + pr) * PIMG
                                  + (sp * 4 + y_i) * 36 + x0;
        unsigned p[3][6];
#pragma unroll
        for (int r = 0; r < 3; ++r) {
            uint4 a0 = *reinterpret_cast<const uint4*>(pc + r * 36);
            uint2 a1 = *reinterpret_cast<const uint2*>(pc + r * 36 + 4);
            p[r][0] = a0.x; p[r][1] = a0.y; p[r][2] = a0.z; p[r][3] = a0.w;
            p[r][4] = a1.x; p[r][5] = a1.y;
        }
#pragma unroll
        for (int oo = 0; oo < 2; ++oo) {
            uint4 wa = *reinterpret_cast<const uint4*>(&wlds[oo][pr][0]);
            uint4 wb = *reinterpret_cast<const uint4*>(&wlds[oo][pr][4]);
            unsigned w8 = wlds[oo][pr][8];
            unsigned wv[9] = {wa.x, wa.y, wa.z, wa.w,
                              wb.x, wb.y, wb.z, wb.w, w8};
#pragma unroll
            for (int kh = 0; kh < 3; ++kh)
#pragma unroll
                for (int kw = 0; kw < 3; ++kw) {
                    unsigned ww = wv[kh * 3 + kw];
#pragma unroll
                    for (int xi = 0; xi < 4; ++xi)
                        acc[oo][xi] = sad16(p[kh][xi + kw], ww, acc[oo][xi]);
                }
        }
    }

    {
        unsigned* dst = &red[cq][pos][0];
#pragma unroll
        for (int z = 0; z < 8; ++z) dst[z] = acc[z >> 2][z & 3];
    }
    __syncthreads();

    const int oo2 = t >> 7;
    const int yy2 = (t >> 5) & 3;
    const int xx2 = t & 31;
    const int pp  = yy2 * 8 + (xx2 >> 2);
    const int z   = oo2 * 4 + (xx2 & 3);
    unsigned total = 0;
#pragma unroll
    for (int q = 0; q < 8; ++q) total += red[q][pp][z];

    const int o  = og * 2 + oo2;
    const int gy = sp * 4 + yy2;

    float v = -(float)total * QINV;
    fout[((b * 64 + o) * 32 + gy) * 32 + xx2] = v;
    float sum = v;
#pragma unroll
    for (int off = 32; off > 0; off >>= 1)
        sum += __shfl_down(sum, off, 64);
    if ((t & 63) == 0) atomicAdd(&sbuf[b * 64 + o], sum);

    // ---- last-block-per-batch gate (fence pattern correctness-validated R4) ----
    __syncthreads();
    if (t == 0) {
        __threadfence();                     // release: fout stores + sbuf atomics
        unsigned tk = __hip_atomic_fetch_add(&cnt[b], 1u, __ATOMIC_ACQ_REL,
                                             __HIP_MEMORY_SCOPE_AGENT);
        lastflag = (tk == 255u);
        if (lastflag) __threadfence();       // acquire: invalidate stale caches
    }
    __syncthreads();
    if (!lastflag) return;

    // SE MLP for batch b
    if (t < 64) gg[t] = sbuf[b * 64 + t] * (1.f / 1024.f);
    __syncthreads();
    if (t < 4) {
        float a = fc1b[t];
#pragma unroll
        for (int c = 0; c < 64; ++c) a += gg[c] * fc1w[t * 64 + c];
        hh[t] = fmaxf(a, 0.f);
    }
    __syncthreads();
    if (t < 64) {
        float zz = fc2b[t];
#pragma unroll
        for (int j = 0; j < 4; ++j) zz += hh[j] * fc2w[t * 4 + j];
        gg[t] = 1.f / (1.f + __expf(-zz));
    }
    __syncthreads();

    // apply gate + shortcut for whole batch: 64 images x 1024 elems
    const float* o2b = fout + b * 65536;
    const float* xb  = x    + b * 65536;
    float*       ob  = out  + b * 65536;
#pragma unroll 8
    for (int i = 0; i < 64; ++i) {
        float g = gg[i];
        int idx = i * 1024 + t * 4;
        float4 vv = *reinterpret_cast<const float4*>(o2b + idx);
        float4 xv = *reinterpret_cast<const float4*>(xb + idx);
        float4 r;
        r.x = vv.x * g + xv.x;
        r.y = vv.y * g + xv.y;
        r.z = vv.z * g + xv.z;
        r.w = vv.w * g + xv.w;
        *reinterpret_cast<float4*>(ob + idx) = r;
    }
}

// ---------------------------------------------------------------------------
extern "C" void kernel_launch(void* const* d_in, const int* in_sizes, int n_in,
                              void* d_out, int out_size, void* d_ws, size_t ws_size,
                              hipStream_t stream)
{
    const float* x    = (const float*)d_in[0];
    const float* bn1g = (const float*)d_in[1];
    const float* bn1b = (const float*)d_in[2];
    const float* bn1m = (const float*)d_in[3];
    const float* bn1v = (const float*)d_in[4];
    const float* w1   = (const float*)d_in[5];
    const float* bn2g = (const float*)d_in[6];
    const float* bn2b = (const float*)d_in[7];
    const float* bn2m = (const float*)d_in[8];
    const float* bn2v = (const float*)d_in[9];
    const float* w2   = (const float*)d_in[10];
    const float* fc1w = (const float*)d_in[11];
    const float* fc1b = (const float*)d_in[12];
    const float* fc2w = (const float*)d_in[13];
    const float* fc2b = (const float*)d_in[14];

    unsigned* ws     = (unsigned*)d_ws;
    float*    sbuf   = (float*)ws;                      // 256 floats
    unsigned* cnt    = ws + 256;                        // 16 counters
    unsigned* qout1p = ws + 512;                        // PPADN
    float*    out2   = (float*)(ws + 512 + PPADN);      // NELEM

    adder1_kernel<<<1024, 256, 0, stream>>>(x, bn1g, bn1b, bn1m, bn1v, w1,
                                            bn2g, bn2b, bn2m, bn2v,
                                            qout1p, sbuf, cnt);
    adder2_kernel<<<1024, 256, 0, stream>>>(qout1p, w2, x,
                                            fc1w, fc1b, fc2w, fc2b,
                                            out2, sbuf, cnt, (float*)d_out);
}

// Round 6
// 124.418 us; speedup vs baseline: 2.9873x; 1.5952x over previous
//
#include <hip/hip_runtime.h>
#include <math.h>

#define NELEM   262144            // 4*64*32*32
#define PIMG    1296              // 36*36 padded image stride per (b,pair)
#define PPADN   165888            // 4*32*36*36 words
#define NHALO   16896             // 128 images * 132 halo words
#define EPS_BN  1e-5f
#define QSC     128.0f
#define QBIAS_F 16384.5f          // bias 16384 + 0.5 rounding
#define QZ_W    0x40004000u       // packed quantized zero
#define QINV    (1.0f / 128.0f)

// v_sad_u16: acc += |a.lo-b.lo| + |a.hi-b.hi|  (two terms per instruction)
__device__ __forceinline__ unsigned sad16(unsigned a, unsigned b, unsigned acc) {
    asm("v_sad_u16 %0, %1, %2, %0" : "+v"(acc) : "v"(a), "v"(b));
    return acc;
}
__device__ __forceinline__ unsigned qu(float v) {
    return (unsigned)(int)fmaf(v, QSC, QBIAS_F);
}

// ---------------------------------------------------------------------------
// adder1: prep fused, fully-coalesced staging (R5-verified structure).
// Grid 1024 = b(4) x og(32: 2 outs) x sp(8: 4-row strips); 256 threads,
// __launch_bounds__(256,4) -> 4 blocks/CU.
// NO cross-block sync of any kind — kernel boundary is the fence.
// ---------------------------------------------------------------------------
__global__ __launch_bounds__(256, 4) void adder1_kernel(
    const float* __restrict__ x,
    const float* __restrict__ g1, const float* __restrict__ b1,
    const float* __restrict__ m1, const float* __restrict__ v1,
    const float* __restrict__ w1,
    const float* __restrict__ g2, const float* __restrict__ b2,
    const float* __restrict__ m2, const float* __restrict__ v2,
    unsigned* __restrict__ qout, float* __restrict__ sbuf)
{
    __shared__ unsigned smem[7808];                   // 31232 B
    unsigned (*xs)[6][36]    = reinterpret_cast<unsigned(*)[6][36]>(smem);         // 6912 w
    unsigned (*red)[32][9]   = reinterpret_cast<unsigned(*)[32][9]>(smem);         // aliases xs
    unsigned (*wlds)[32][12] = reinterpret_cast<unsigned(*)[32][12]>(smem + 6912); // 768 w
    float* binv = reinterpret_cast<float*>(smem + 7680);                           // 64 f
    float* bbet = binv + 64;                                                       // 64 f

    const int blk = blockIdx.x;
    const int sp  = blk & 7;                 // rows [sp*4, sp*4+4)
    const int og  = (blk >> 3) & 31;
    const int b   = blk >> 8;
    const int t   = threadIdx.x;

    // ---- side duties: sbuf zero (block 0) + qout1p halo ring ----
    const int gid = blk * 256 + t;
    if (gid < 256) sbuf[gid] = 0.f;
    if (gid < NHALO) {
        int img = gid / 132;
        int j   = gid - img * 132;
        int r, c;
        if (j < 34)       { r = 0;           c = j;       }
        else if (j < 68)  { r = 33;          c = j - 34;  }
        else if (j < 100) { r = j - 68 + 1;  c = 0;       }
        else              { r = j - 100 + 1; c = 33;      }
        qout[img * PIMG + r * 36 + c] = QZ_W;
    }

    // ---- bn1 consts ----
    if (t < 64) {
        float iv = g1[t] * rsqrtf(v1[t] + EPS_BN);
        binv[t] = iv;
        bbet[t] = b1[t] - m1[t] * iv;
    }

    // ---- QZ fill of xs (padding cols 0,33..35 + out-of-range rows) ----
    for (int u = t; u < 1728; u += 256)      // 6912 words / 4
        reinterpret_cast<uint4*>(smem)[u] = make_uint4(QZ_W, QZ_W, QZ_W, QZ_W);

    // ---- w1 quant staging: contiguous slice og*1152 .. +1152, coalesced ----
    {
        unsigned short* wh = reinterpret_cast<unsigned short*>(wlds);
        const float* wbase = w1 + og * 1152;
        for (int u = t; u < 1152; u += 256) {
            int o_i = u / 576;
            int rem = u - o_i * 576;
            int c   = rem / 9;
            int kk  = rem - c * 9;
            wh[((o_i * 32 + (c >> 1)) * 12 + kk) * 2 + (c & 1)] =
                (unsigned short)qu(wbase[u]);
        }
    }
    __syncthreads();

    // ---- coalesced x staging: 6 rows x 64 ch x 32 cols, u16 half-writes ----
    {
        unsigned short* xh = reinterpret_cast<unsigned short*>(smem);
        for (int u = t; u < 12288; u += 256) {
            int lr  = u >> 11;               // 0..5
            int c   = (u >> 5) & 63;
            int col = u & 31;
            int xrow = sp * 4 + lr - 1;      // -1..34
            if ((unsigned)xrow < 32u) {
                float xv = x[(b * 64 + c) * 1024 + xrow * 32 + col];
                unsigned q = qu(fmaxf(fmaf(xv, binv[c], bbet[c]), 0.f));
                xh[((c >> 1) * 216 + lr * 36 + col + 1) * 2 + (c & 1)] =
                    (unsigned short)q;
            }
        }
    }
    __syncthreads();

    // ---- SAD compute (R1/R3-verified body) ----
    const int pos = t & 31;
    const int cq  = t >> 5;                  // 0..7, 4 pairs each
    const int y_i = pos >> 3;                // 0..3
    const int x0  = (pos & 7) * 4;           // 0..28

    unsigned acc[2][4];
#pragma unroll
    for (int oo = 0; oo < 2; ++oo)
#pragma unroll
        for (int xi = 0; xi < 4; ++xi) acc[oo][xi] = 0u;

#pragma unroll
    for (int j = 0; j < 4; ++j) {
        const int pr = cq * 4 + j;
        unsigned p[3][6];
#pragma unroll
        for (int r = 0; r < 3; ++r) {
            const unsigned* src = &xs[pr][y_i + r][x0];
            uint4 a0 = *reinterpret_cast<const uint4*>(src);
            uint2 a1 = *reinterpret_cast<const uint2*>(src + 4);
            p[r][0] = a0.x; p[r][1] = a0.y; p[r][2] = a0.z; p[r][3] = a0.w;
            p[r][4] = a1.x; p[r][5] = a1.y;
        }
#pragma unroll
        for (int oo = 0; oo < 2; ++oo) {
            uint4 wa = *reinterpret_cast<const uint4*>(&wlds[oo][pr][0]);
            uint4 wb = *reinterpret_cast<const uint4*>(&wlds[oo][pr][4]);
            unsigned w8 = wlds[oo][pr][8];
            unsigned wv[9] = {wa.x, wa.y, wa.z, wa.w,
                              wb.x, wb.y, wb.z, wb.w, w8};
#pragma unroll
            for (int kh = 0; kh < 3; ++kh)
#pragma unroll
                for (int kw = 0; kw < 3; ++kw) {
                    unsigned ww = wv[kh * 3 + kw];
#pragma unroll
                    for (int xi = 0; xi < 4; ++xi)
                        acc[oo][xi] = sad16(p[kh][xi + kw], ww, acc[oo][xi]);
                }
        }
    }
    __syncthreads();                          // xs reads done before red aliases

    {
        unsigned* dst = &red[cq][pos][0];
#pragma unroll
        for (int z = 0; z < 8; ++z) dst[z] = acc[z >> 2][z & 3];
    }
    __syncthreads();

    const int oo2 = t >> 7;
    const int yy2 = (t >> 5) & 3;
    const int xx2 = t & 31;
    const int pp  = yy2 * 8 + (xx2 >> 2);
    const int z   = oo2 * 4 + (xx2 & 3);
    unsigned total = 0;
#pragma unroll
    for (int q = 0; q < 8; ++q) total += red[q][pp][z];

    const int o  = og * 2 + oo2;             // wave-uniform
    const int gy = sp * 4 + yy2;

    // bn2 consts inline (wave-uniform o -> broadcast loads; R3-verified)
    float inv = g2[o] * rsqrtf(v2[o] + EPS_BN);
    float cc0 = -inv * QINV;
    float cc1 = b2[o] - m2[o] * inv;
    float a2  = fmaxf(fmaf((float)total, cc0, cc1), 0.f);
    unsigned short qv = (unsigned short)(int)fmaf(a2, QSC, QBIAS_F);
    size_t widx = (size_t)(b * 32 + (o >> 1)) * PIMG + (gy + 1) * 36 + (xx2 + 1);
    reinterpret_cast<unsigned short*>(qout)[widx * 2 + (o & 1)] = qv;
}

// ---------------------------------------------------------------------------
// adder2: R1-verified layer-2 body, w2 quantized inline (R3-verified).
// NO ticket / NO fence / NO gate tail — those cost ~100 µs in R5.
// Writes float out2 + SE spatial-sum atomics into sbuf (R1-verified).
// ---------------------------------------------------------------------------
__global__ __launch_bounds__(256, 4) void adder2_kernel(
    const unsigned* __restrict__ qsrc, const float* __restrict__ w2,
    float* __restrict__ fout, float* __restrict__ sbuf)
{
    __shared__ unsigned wlds[2][32][12];     // 3072 B
    __shared__ unsigned red[8][32][9];       // 9216 B

    const int blk = blockIdx.x;
    const int sp  = blk & 7;
    const int og  = (blk >> 3) & 31;
    const int b   = blk >> 8;
    const int t   = threadIdx.x;
    const int pos = t & 31;
    const int cq  = t >> 5;
    const int y_i = pos >> 3;
    const int x0  = (pos & 7) * 4;

    for (int i = t; i < 576; i += 256) {
        int o_i = i / 288;
        int rem = i - o_i * 288;
        int pr  = rem / 9;
        int kk  = rem - pr * 9;
        int woff = ((og * 2 + o_i) * 64 + pr * 2) * 9 + kk;
        wlds[o_i][pr][kk] = qu(w2[woff]) | (qu(w2[woff + 9]) << 16);
    }
    __syncthreads();

    unsigned acc[2][4];
#pragma unroll
    for (int oo = 0; oo < 2; ++oo)
#pragma unroll
        for (int xi = 0; xi < 4; ++xi) acc[oo][xi] = 0u;

#pragma unroll
    for (int j = 0; j < 4; ++j) {
        const int pr = cq * 4 + j;
        const unsigned* pc = qsrc + (size_t)(b * 32 + pr) * PIMG
                                  + (sp * 4 + y_i) * 36 + x0;
        unsigned p[3][6];
#pragma unroll
        for (int r = 0; r < 3; ++r) {
            uint4 a0 = *reinterpret_cast<const uint4*>(pc + r * 36);
            uint2 a1 = *reinterpret_cast<const uint2*>(pc + r * 36 + 4);
            p[r][0] = a0.x; p[r][1] = a0.y; p[r][2] = a0.z; p[r][3] = a0.w;
            p[r][4] = a1.x; p[r][5] = a1.y;
        }
#pragma unroll
        for (int oo = 0; oo < 2; ++oo) {
            uint4 wa = *reinterpret_cast<const uint4*>(&wlds[oo][pr][0]);
            uint4 wb = *reinterpret_cast<const uint4*>(&wlds[oo][pr][4]);
            unsigned w8 = wlds[oo][pr][8];
            unsigned wv[9] = {wa.x, wa.y, wa.z, wa.w,
                              wb.x, wb.y, wb.z, wb.w, w8};
#pragma unroll
            for (int kh = 0; kh < 3; ++kh)
#pragma unroll
                for (int kw = 0; kw < 3; ++kw) {
                    unsigned ww = wv[kh * 3 + kw];
#pragma unroll
                    for (int xi = 0; xi < 4; ++xi)
                        acc[oo][xi] = sad16(p[kh][xi + kw], ww, acc[oo][xi]);
                }
        }
    }

    {
        unsigned* dst = &red[cq][pos][0];
#pragma unroll
        for (int z = 0; z < 8; ++z) dst[z] = acc[z >> 2][z & 3];
    }
    __syncthreads();

    const int oo2 = t >> 7;
    const int yy2 = (t >> 5) & 3;
    const int xx2 = t & 31;
    const int pp  = yy2 * 8 + (xx2 >> 2);
    const int z   = oo2 * 4 + (xx2 & 3);
    unsigned total = 0;
#pragma unroll
    for (int q = 0; q < 8; ++q) total += red[q][pp][z];

    const int o  = og * 2 + oo2;
    const int gy = sp * 4 + yy2;

    float v = -(float)total * QINV;
    fout[((b * 64 + o) * 32 + gy) * 32 + xx2] = v;
    float sum = v;
#pragma unroll
    for (int off = 32; off > 0; off >>= 1)
        sum += __shfl_down(sum, off, 64);
    if ((t & 63) == 0) atomicAdd(&sbuf[b * 64 + o], sum);
}

// ---------------------------------------------------------------------------
// SE gate + apply + shortcut. 256 blocks (one per b,o image) x 256 threads.
// (R1-verified; kernel boundary provides the coherence fence for free.)
// ---------------------------------------------------------------------------
__global__ __launch_bounds__(256) void gate_kernel(
    const float* __restrict__ out2, const float* __restrict__ x,
    const float* __restrict__ sbuf,
    const float* __restrict__ fc1w, const float* __restrict__ fc1b,
    const float* __restrict__ fc2w, const float* __restrict__ fc2b,
    float* __restrict__ out)
{
    const int bo = blockIdx.x;
    const int b  = bo >> 6;
    const int o  = bo & 63;
    const int t  = threadIdx.x;

    __shared__ float ss[64];
    if (t < 64) ss[t] = sbuf[b * 64 + t] * (1.f / 1024.f);
    __syncthreads();

    float h[4];
#pragma unroll
    for (int j = 0; j < 4; ++j) {
        float a = fc1b[j];
#pragma unroll
        for (int c = 0; c < 64; ++c) a += ss[c] * fc1w[j * 64 + c];
        h[j] = fmaxf(a, 0.f);
    }
    float zz = fc2b[o];
#pragma unroll
    for (int j = 0; j < 4; ++j) zz += h[j] * fc2w[o * 4 + j];
    float g = 1.f / (1.f + __expf(-zz));

    const int base = bo * 1024 + t * 4;
    float4 v  = *reinterpret_cast<const float4*>(out2 + base);
    float4 xv = *reinterpret_cast<const float4*>(x + base);
    float4 r;
    r.x = v.x * g + xv.x;
    r.y = v.y * g + xv.y;
    r.z = v.z * g + xv.z;
    r.w = v.w * g + xv.w;
    *reinterpret_cast<float4*>(out + base) = r;
}

// ---------------------------------------------------------------------------
extern "C" void kernel_launch(void* const* d_in, const int* in_sizes, int n_in,
                              void* d_out, int out_size, void* d_ws, size_t ws_size,
                              hipStream_t stream)
{
    const float* x    = (const float*)d_in[0];
    const float* bn1g = (const float*)d_in[1];
    const float* bn1b = (const float*)d_in[2];
    const float* bn1m = (const float*)d_in[3];
    const float* bn1v = (const float*)d_in[4];
    const float* w1   = (const float*)d_in[5];
    const float* bn2g = (const float*)d_in[6];
    const float* bn2b = (const float*)d_in[7];
    const float* bn2m = (const float*)d_in[8];
    const float* bn2v = (const float*)d_in[9];
    const float* w2   = (const float*)d_in[10];
    const float* fc1w = (const float*)d_in[11];
    const float* fc1b = (const float*)d_in[12];
    const float* fc2w = (const float*)d_in[13];
    const float* fc2b = (const float*)d_in[14];

    unsigned* ws     = (unsigned*)d_ws;
    float*    sbuf   = (float*)ws;                      // 256 floats
    unsigned* qout1p = ws + 256;                        // PPADN
    float*    out2   = (float*)(ws + 256 + PPADN);      // NELEM

    adder1_kernel<<<1024, 256, 0, stream>>>(x, bn1g, bn1b, bn1m, bn1v, w1,
                                            bn2g, bn2b, bn2m, bn2v,
                                            qout1p, sbuf);
    adder2_kernel<<<1024, 256, 0, stream>>>(qout1p, w2, out2, sbuf);
    gate_kernel<<<256, 256, 0, stream>>>(out2, x, sbuf, fc1w, fc1b, fc2w, fc2b,
                                         (float*)d_out);
}

// Round 7
// 110.685 us; speedup vs baseline: 3.3579x; 1.1241x over previous
//
#include <hip/hip_runtime.h>
#include <math.h>

#define NELEM   262144            // 4*64*32*32
#define NPAIRW  18432             // 64 o * 32 pairs * 9
#define PIMG    1296              // 36*36 padded image stride per (b,pair)
#define PPADN   165888            // 4*32*36*36 words
#define NPAIR   147968            // 4*32*34*34
#define EPS_BN  1e-5f
#define QSC     128.0f
#define QBIAS_F 16384.5f          // bias 16384 + 0.5 rounding
#define QZ_W    0x40004000u       // packed quantized zero
#define QINV    (1.0f / 128.0f)

// v_sad_u16: acc += |a.lo-b.lo| + |a.hi-b.hi|  (two terms per instruction)
__device__ __forceinline__ unsigned sad16(unsigned a, unsigned b, unsigned acc) {
    asm("v_sad_u16 %0, %1, %2, %0" : "+v"(acc) : "v"(a), "v"(b));
    return acc;
}
__device__ __forceinline__ unsigned qu(float v) {
    return (unsigned)(int)fmaf(v, QSC, QBIAS_F);
}

// ---------------------------------------------------------------------------
// prep: pair-packed quantized padded input qxp[4][32][36][36] (u16x2 words),
// qout1p halo words, pair-packed weights qw1p/qw2p, bn2 consts, sbuf zero.
// Fully parallel one-round dispatch — measured faster than any fused-prep
// variant (R3: +6.5 us, R6: +16.2 us vs this structure).
// ---------------------------------------------------------------------------
__global__ __launch_bounds__(256) void prep_kernel(
    const float* __restrict__ x,
    const float* __restrict__ g1, const float* __restrict__ b1,
    const float* __restrict__ m1, const float* __restrict__ v1,
    const float* __restrict__ w1,
    const float* __restrict__ g2, const float* __restrict__ b2,
    const float* __restrict__ m2, const float* __restrict__ v2,
    const float* __restrict__ w2,
    unsigned* __restrict__ qxp, unsigned* __restrict__ qout1p,
    unsigned* __restrict__ qw1p, unsigned* __restrict__ qw2p,
    float* __restrict__ bn2c, float* __restrict__ sbuf)
{
    int i = blockIdx.x * 256 + threadIdx.x;
    if (i < NPAIR) {
        int bp  = i / 1156;                       // b*32 + pair
        int rc  = i - bp * 1156;
        int r   = rc / 34;
        int col = rc - r * 34;
        bool interior = (r > 0 && r < 33 && col > 0 && col < 33);
        unsigned q = QZ_W;
        if (interior) {
            int b  = bp >> 5;
            int c0 = (bp & 31) * 2;
            float inv0 = g1[c0] * rsqrtf(v1[c0] + EPS_BN);
            float bet0 = b1[c0] - m1[c0] * inv0;
            float inv1 = g1[c0 + 1] * rsqrtf(v1[c0 + 1] + EPS_BN);
            float bet1 = b1[c0 + 1] - m1[c0 + 1] * inv1;
            int off = (b * 64 + c0) * 1024 + (r - 1) * 32 + (col - 1);
            float a0 = fmaxf(fmaf(x[off],        inv0, bet0), 0.f);
            float a1 = fmaxf(fmaf(x[off + 1024], inv1, bet1), 0.f);
            q = qu(a0) | (qu(a1) << 16);
        }
        int pidx = bp * PIMG + r * 36 + col;
        qxp[pidx] = q;
        if (!interior) qout1p[pidx] = QZ_W;
        return;
    }
    int k = i - NPAIR;
    if (k < NPAIRW) {
        int o   = k / 288;
        int rem = k - o * 288;
        int pr  = rem / 9;
        int kk  = rem - pr * 9;
        int woff = (o * 64 + pr * 2) * 9 + kk;
        qw1p[k] = qu(w1[woff]) | (qu(w1[woff + 9]) << 16);
        return;
    }
    int l = k - NPAIRW;
    if (l < NPAIRW) {
        int o   = l / 288;
        int rem = l - o * 288;
        int pr  = rem / 9;
        int kk  = rem - pr * 9;
        int woff = (o * 64 + pr * 2) * 9 + kk;
        qw2p[l] = qu(w2[woff]) | (qu(w2[woff + 9]) << 16);
        return;
    }
    int m = l - NPAIRW;
    if (m < 64) {
        float inv = g2[m] * rsqrtf(v2[m] + EPS_BN);
        bn2c[m]      = -inv * QINV;               // maps u32 acc -> bn2 pre-act
        bn2c[m + 64] = b2[m] - m2[m] * inv;
        return;
    }
    int s = m - 64;
    if (s >= 0 && s < 256) sbuf[s] = 0.f;
}

// ---------------------------------------------------------------------------
// Adder2d on pair-packed u16 data (v_sad_u16).
// Grid 1024 = b(4) x og(32: 2 outputs) x sp(8: 4-row strips); 256 threads.
// pos = t&31: y_i = pos>>3 (0..3), x0 = (pos&7)*4 (4-wide); cq = t>>5 (0..7)
// -> 4 channel-pairs each (serial j loop, patch regs reused).
// Tail: ALL 256 threads produce one output each (2 o x 4 rows x 32 cols),
// 8-deep LDS reduction, red padded to stride 9 (9 coprime 32 -> no bank
// conflict on write, ~2-way on read).
// __launch_bounds__(256,4): 128 VGPR budget, 4 blocks/CU co-resident.
// MODE 0: writes quant(relu(bn2(-acc))) u16 half into packed qout.
// MODE 1: writes float out2 + SE spatial-sum atomics into sbuf.
// NO cross-block sync anywhere — kernel boundaries are the fences
// (R4 spin-barrier: +260 us; R5 fence+ticket tail: +90 us; R3/R6 fused
// prep: +6.5/+16.2 us — all regress vs this 4-dispatch structure).
// ---------------------------------------------------------------------------
template<int MODE>
__global__ __launch_bounds__(256, 4) void adder_kernel(
    const unsigned* __restrict__ qsrc, const unsigned* __restrict__ qwp,
    const float* __restrict__ bn2c,
    unsigned* __restrict__ qout, float* __restrict__ fout,
    float* __restrict__ sbuf)
{
    __shared__ unsigned wlds[2][32][12];     // 3072 B
    __shared__ unsigned red[8][32][9];       // 9216 B -> 12 KB total

    const int blk = blockIdx.x;
    const int sp  = blk & 7;                 // rows [sp*4, sp*4+4)
    const int og  = (blk >> 3) & 31;
    const int b   = blk >> 8;
    const int t   = threadIdx.x;
    const int pos = t & 31;
    const int cq  = t >> 5;                  // 0..7, 4 pairs each
    const int y_i = pos >> 3;                // 0..3
    const int x0  = (pos & 7) * 4;           // 0..28

    // weight staging: 2 o x 32 pairs x 9 words (~2.25 words/thread)
    for (int i = t; i < 576; i += 256) {
        int o_i = i / 288;
        int rem = i - o_i * 288;
        int pr  = rem / 9;
        int kk  = rem - pr * 9;
        wlds[o_i][pr][kk] = qwp[((og * 2 + o_i) * 32 + pr) * 9 + kk];
    }
    __syncthreads();

    unsigned acc[2][4];
#pragma unroll
    for (int oo = 0; oo < 2; ++oo)
#pragma unroll
        for (int xi = 0; xi < 4; ++xi) acc[oo][xi] = 0u;

#pragma unroll
    for (int j = 0; j < 4; ++j) {
        const int pr = cq * 4 + j;
        const unsigned* pc = qsrc + (size_t)(b * 32 + pr) * PIMG
                                  + (sp * 4 + y_i) * 36 + x0;
        unsigned p[3][6];                    // 6 words/row: x4 + x2 loads
#pragma unroll
        for (int r = 0; r < 3; ++r) {
            uint4 a0 = *reinterpret_cast<const uint4*>(pc + r * 36);
            uint2 a1 = *reinterpret_cast<const uint2*>(pc + r * 36 + 4);
            p[r][0] = a0.x; p[r][1] = a0.y; p[r][2] = a0.z; p[r][3] = a0.w;
            p[r][4] = a1.x; p[r][5] = a1.y;
        }
#pragma unroll
        for (int oo = 0; oo < 2; ++oo) {
            uint4 wa = *reinterpret_cast<const uint4*>(&wlds[oo][pr][0]);
            uint4 wb = *reinterpret_cast<const uint4*>(&wlds[oo][pr][4]);
            unsigned w8 = wlds[oo][pr][8];
            unsigned wv[9] = {wa.x, wa.y, wa.z, wa.w,
                              wb.x, wb.y, wb.z, wb.w, w8};
#pragma unroll
            for (int kh = 0; kh < 3; ++kh)
#pragma unroll
                for (int kw = 0; kw < 3; ++kw) {
                    unsigned ww = wv[kh * 3 + kw];
#pragma unroll
                    for (int xi = 0; xi < 4; ++xi)
                        acc[oo][xi] = sad16(p[kh][xi + kw], ww, acc[oo][xi]);
                }
        }
    }

    // ---- cq reduction via LDS (stride-9 padded: conflict-free writes) ----
    {
        unsigned* dst = &red[cq][pos][0];
#pragma unroll
        for (int z = 0; z < 8; ++z) dst[z] = acc[z >> 2][z & 3];
    }
    __syncthreads();

    // 256 outputs: 2 o x 4 rows x 32 cols — every thread produces one
    const int oo2 = t >> 7;                  // wave-pair uniform
    const int yy2 = (t >> 5) & 3;
    const int xx2 = t & 31;
    const int pp  = yy2 * 8 + (xx2 >> 2);
    const int z   = oo2 * 4 + (xx2 & 3);
    unsigned total = 0;
#pragma unroll
    for (int q = 0; q < 8; ++q) total += red[q][pp][z];

    const int o  = og * 2 + oo2;             // wave-uniform
    const int gy = sp * 4 + yy2;

    if (MODE == 0) {
        float a2 = fmaxf(fmaf((float)total, bn2c[o], bn2c[o + 64]), 0.f);
        unsigned short qv = (unsigned short)(int)fmaf(a2, QSC, QBIAS_F);
        size_t widx = (size_t)(b * 32 + (o >> 1)) * PIMG + (gy + 1) * 36 + (xx2 + 1);
        reinterpret_cast<unsigned short*>(qout)[widx * 2 + (o & 1)] = qv;
    } else {
        float v = -(float)total * QINV;
        fout[((b * 64 + o) * 32 + gy) * 32 + xx2] = v;
        float sum = v;                        // wave covers 2 rows of same o
#pragma unroll
        for (int off = 32; off > 0; off >>= 1)
            sum += __shfl_down(sum, off, 64);
        if ((t & 63) == 0) atomicAdd(&sbuf[b * 64 + o], sum);
    }
}

// ---------------------------------------------------------------------------
// SE gate + apply + shortcut. 256 blocks (one per b,o image) x 256 threads.
// ---------------------------------------------------------------------------
__global__ __launch_bounds__(256) void gate_kernel(
    const float* __restrict__ out2, const float* __restrict__ x,
    const float* __restrict__ sbuf,
    const float* __restrict__ fc1w, const float* __restrict__ fc1b,
    const float* __restrict__ fc2w, const float* __restrict__ fc2b,
    float* __restrict__ out)
{
    const int bo = blockIdx.x;
    const int b  = bo >> 6;
    const int o  = bo & 63;
    const int t  = threadIdx.x;

    __shared__ float ss[64];
    if (t < 64) ss[t] = sbuf[b * 64 + t] * (1.f / 1024.f);
    __syncthreads();

    float h[4];
#pragma unroll
    for (int j = 0; j < 4; ++j) {
        float a = fc1b[j];
#pragma unroll
        for (int c = 0; c < 64; ++c) a += ss[c] * fc1w[j * 64 + c];
        h[j] = fmaxf(a, 0.f);
    }
    float zz = fc2b[o];
#pragma unroll
    for (int j = 0; j < 4; ++j) zz += h[j] * fc2w[o * 4 + j];
    float g = 1.f / (1.f + __expf(-zz));

    const int base = bo * 1024 + t * 4;
    float4 v  = *reinterpret_cast<const float4*>(out2 + base);
    float4 xv = *reinterpret_cast<const float4*>(x + base);
    float4 r;
    r.x = v.x * g + xv.x;
    r.y = v.y * g + xv.y;
    r.z = v.z * g + xv.z;
    r.w = v.w * g + xv.w;
    *reinterpret_cast<float4*>(out + base) = r;
}

// ---------------------------------------------------------------------------
extern "C" void kernel_launch(void* const* d_in, const int* in_sizes, int n_in,
                              void* d_out, int out_size, void* d_ws, size_t ws_size,
                              hipStream_t stream)
{
    const float* x    = (const float*)d_in[0];
    const float* bn1g = (const float*)d_in[1];
    const float* bn1b = (const float*)d_in[2];
    const float* bn1m = (const float*)d_in[3];
    const float* bn1v = (const float*)d_in[4];
    const float* w1   = (const float*)d_in[5];
    const float* bn2g = (const float*)d_in[6];
    const float* bn2b = (const float*)d_in[7];
    const float* bn2m = (const float*)d_in[8];
    const float* bn2v = (const float*)d_in[9];
    const float* w2   = (const float*)d_in[10];
    const float* fc1w = (const float*)d_in[11];
    const float* fc1b = (const float*)d_in[12];
    const float* fc2w = (const float*)d_in[13];
    const float* fc2b = (const float*)d_in[14];

    unsigned* ws     = (unsigned*)d_ws;
    unsigned* qxp    = ws;                              // PPADN
    unsigned* qout1p = ws + PPADN;                      // PPADN
    float*    out2   = (float*)(ws + 2 * PPADN);        // NELEM
    unsigned* qw1p   = ws + 2 * PPADN + NELEM;          // NPAIRW
    unsigned* qw2p   = ws + 2 * PPADN + NELEM + NPAIRW; // NPAIRW
    float*    bn2c   = (float*)(ws + 2 * PPADN + NELEM + 2 * NPAIRW);        // 128
    float*    sbuf   = (float*)(ws + 2 * PPADN + NELEM + 2 * NPAIRW + 128);  // 256

    // segments: NPAIR + NPAIRW + NPAIRW + 64 + 256 = 185,152 -> 724 blocks
    prep_kernel<<<724, 256, 0, stream>>>(x, bn1g, bn1b, bn1m, bn1v, w1,
                                         bn2g, bn2b, bn2m, bn2v, w2,
                                         qxp, qout1p, qw1p, qw2p, bn2c, sbuf);
    adder_kernel<0><<<1024, 256, 0, stream>>>(qxp,    qw1p, bn2c, qout1p, nullptr, nullptr);
    adder_kernel<1><<<1024, 256, 0, stream>>>(qout1p, qw2p, nullptr, nullptr, out2, sbuf);
    gate_kernel<<<256, 256, 0, stream>>>(out2, x, sbuf, fc1w, fc1b, fc2w, fc2b,
                                         (float*)d_out);
}